// Round 1
// baseline (223.369 us; speedup 1.0000x reference)
//
#include <hip/hip_runtime.h>
#include <math.h>

#define BB 4
#define CC 128
#define HF 128
#define WF 128

// ---------- helpers with fp-contract OFF to bit-match the numpy reference ----------
__device__ __forceinline__ float wsum3(float a, float wa, float b, float wb, float c, float wc) {
#pragma clang fp contract(off)
    {
        float r = a * wa;
        r = r + b * wb;
        r = r + c * wc;
        return r;
    }
}

__device__ __forceinline__ float to_pix(float cv, int Wm1, int WFm1) {
#pragma clang fp contract(off)
    {
        float g = cv / (float)Wm1 * 2.0f - 1.0f;
        return (g + 1.0f) * 0.5f * (float)WFm1;
    }
}

// ---------- 1. NCHW -> NHWC transpose of feature_map ----------
__global__ void transpose_fm(const float* __restrict__ fm, float* __restrict__ fmT) {
    __shared__ float tile[32][33];
    int b = blockIdx.z;
    int hw0 = blockIdx.x * 32;   // position tile base
    int c0 = blockIdx.y * 32;    // channel tile base
    int tx = threadIdx.x;        // 0..31
    int ty = threadIdx.y;        // 0..7
    const float* in = fm + (size_t)b * CC * HF * WF;
    float* out = fmT + (size_t)b * HF * WF * CC;
    #pragma unroll
    for (int i = ty; i < 32; i += 8)
        tile[i][tx] = in[(size_t)(c0 + i) * (HF * WF) + hw0 + tx];
    __syncthreads();
    #pragma unroll
    for (int i = ty; i < 32; i += 8)
        out[(size_t)(hw0 + i) * CC + c0 + tx] = tile[tx][i];
}

// ---------- 2. depth buffer init ----------
__global__ void depth_init(float* __restrict__ depth, const int* pH, const int* pW) {
    int total = BB * (*pH) * (*pW);
    for (int i = blockIdx.x * blockDim.x + threadIdx.x; i < total; i += gridDim.x * blockDim.x)
        depth[i] = INFINITY;
}

// ---------- 3. scatter-min of vertex depths ----------
__global__ void depth_scatter(const float* __restrict__ v2d, const float* __restrict__ v3d,
                              float* __restrict__ depth, int Nv, const int* pH, const int* pW) {
    int H = *pH, W = *pW;
    int i = blockIdx.x * blockDim.x + threadIdx.x;
    if (i >= BB * Nv) return;
    int b = i / Nv, v = i - b * Nv;
    float x = v2d[((size_t)b * Nv + v) * 2 + 0];
    float y = v2d[((size_t)b * Nv + v) * 2 + 1];
    int xv = (int)rintf(x);
    int yv = (int)rintf(y);
    if (xv < 0 || xv >= W || yv < 0 || yv >= H) return;
    float z = v3d[((size_t)b * Nv + v) * 3 + 2];
    // z > 0 always, inf init: int compare == float compare for non-negative floats
    atomicMin((int*)&depth[(size_t)b * H * W + (size_t)yv * W + xv], __float_as_int(z));
}

// ---------- 4. per-point setup: centers, angle, visibility, bilinear params ----------
__global__ void point_setup(const float* __restrict__ v2d, const float* __restrict__ v3d,
                            const int* __restrict__ parents, const float* __restrict__ bary,
                            const float* __restrict__ depth,
                            float* __restrict__ out_vw, float* __restrict__ out_c3,
                            float4* __restrict__ params,
                            int N, int Nv, int K, const int* pH, const int* pW) {
    int H = *pH, W = *pW;
    int idx = blockIdx.x * blockDim.x + threadIdx.x;
    if (idx >= BB * N) return;
    int b = idx / N, n = idx - b * N;
    int k = n % K;
    float w0 = bary[k * 3 + 0], w1 = bary[k * 3 + 1], w2 = bary[k * 3 + 2];
    int i0 = parents[(size_t)n * 3 + 0];
    int i1 = parents[(size_t)n * 3 + 1];
    int i2 = parents[(size_t)n * 3 + 2];
    const float* v2b = v2d + (size_t)b * Nv * 2;
    const float* v3b = v3d + (size_t)b * Nv * 3;
    float ax = v2b[(size_t)i0 * 2], ay = v2b[(size_t)i0 * 2 + 1];
    float bx = v2b[(size_t)i1 * 2], by = v2b[(size_t)i1 * 2 + 1];
    float cx = v2b[(size_t)i2 * 2], cy = v2b[(size_t)i2 * 2 + 1];
    float c2x = wsum3(ax, w0, bx, w1, cx, w2);
    float c2y = wsum3(ay, w0, by, w1, cy, w2);
    float a0 = v3b[(size_t)i0 * 3], a1 = v3b[(size_t)i0 * 3 + 1], a2 = v3b[(size_t)i0 * 3 + 2];
    float b0 = v3b[(size_t)i1 * 3], b1 = v3b[(size_t)i1 * 3 + 1], b2 = v3b[(size_t)i1 * 3 + 2];
    float c0 = v3b[(size_t)i2 * 3], c1 = v3b[(size_t)i2 * 3 + 1], c2 = v3b[(size_t)i2 * 3 + 2];
    float c3x = wsum3(a0, w0, b0, w1, c0, w2);
    float c3y = wsum3(a1, w0, b1, w1, c1, w2);
    float c3z = wsum3(a2, w0, b2, w1, c2, w2);
    // face normal
    float e1x = b0 - a0, e1y = b1 - a1, e1z = b2 - a2;
    float e2x = c0 - a0, e2y = c1 - a1, e2z = c2 - a2;
    float nx = e1y * e2z - e1z * e2y;
    float ny = e1z * e2x - e1x * e2z;
    float nz = e1x * e2y - e1y * e2x;
    float nn = sqrtf(nx * nx + ny * ny + nz * nz) + 1e-8f;
    nx /= nn; ny /= nn; nz /= nn;
    float vn = sqrtf(c3x * c3x + c3y * c3y + c3z * c3z) + 1e-8f;
    float vx = -c3x / vn, vy = -c3y / vn, vz = -c3z / vn;
    float ang = fmaxf(nx * vx + ny * vy + nz * vz, 0.0f);
    // visibility
    int xc = (int)rintf(c2x); xc = min(max(xc, 0), W - 1);
    int yc = (int)rintf(c2y); yc = min(max(yc, 0), H - 1);
    float dsamp = depth[(size_t)b * H * W + (size_t)yc * W + xc];
    bool visible = (c3z <= dsamp + 1e-3f) || isinf(dsamp);
    out_vw[idx] = visible ? ang : 0.0f;
    out_c3[(size_t)idx * 3 + 0] = c3x;
    out_c3[(size_t)idx * 3 + 1] = c3y;
    out_c3[(size_t)idx * 3 + 2] = c3z;
    // bilinear params
    float px = to_pix(c2x, W - 1, WF - 1);
    float py = to_pix(c2y, H - 1, HF - 1);
    float x0f = floorf(px), y0f = floorf(py);
    float4 p;
    p.x = __int_as_float((int)x0f);
    p.y = __int_as_float((int)y0f);
    p.z = px - x0f;
    p.w = py - y0f;
    params[idx] = p;
}

// ---------- 5. bilinear feature gather: 32 lanes per point, float4 per lane ----------
__global__ void gather_feats(const float* __restrict__ fmT, const float4* __restrict__ params,
                             float* __restrict__ out, int N) {
    int gid = blockIdx.x * blockDim.x + threadIdx.x;
    int lane = gid & 31;
    int point = gid >> 5;   // b*N + n
    if (point >= BB * N) return;
    float4 p = params[point];
    int x0 = __float_as_int(p.x);
    int y0 = __float_as_int(p.y);
    float wx = p.z, wy = p.w;
    int b = point / N;
    const float* base = fmT + (size_t)b * HF * WF * CC;
    float w00 = (1.0f - wx) * (1.0f - wy);
    float w10 = wx * (1.0f - wy);
    float w01 = (1.0f - wx) * wy;
    float w11 = wx * wy;
    int co = lane * 4;
    float4 acc = {0.0f, 0.0f, 0.0f, 0.0f};
#define CORNER(XI, YI, WGT)                                                     \
    do {                                                                        \
        int X = (XI), Y = (YI);                                                 \
        if (X >= 0 && X < WF && Y >= 0 && Y < HF) {                             \
            float4 v = *(const float4*)(base + ((size_t)Y * WF + X) * CC + co); \
            acc.x += (WGT) * v.x; acc.y += (WGT) * v.y;                         \
            acc.z += (WGT) * v.z; acc.w += (WGT) * v.w;                         \
        }                                                                       \
    } while (0)
    CORNER(x0, y0, w00);
    CORNER(x0 + 1, y0, w10);
    CORNER(x0, y0 + 1, w01);
    CORNER(x0 + 1, y0 + 1, w11);
#undef CORNER
    ((float4*)out)[(size_t)point * (CC / 4) + lane] = acc;
}

extern "C" void kernel_launch(void* const* d_in, const int* in_sizes, int n_in,
                              void* d_out, int out_size, void* d_ws, size_t ws_size,
                              hipStream_t stream) {
    const float* fm = (const float*)d_in[0];
    const float* v2d = (const float*)d_in[1];
    const float* v3d = (const float*)d_in[2];
    const int* parents = (const int*)d_in[3];
    const float* bary = (const float*)d_in[4];
    const int* pH = (const int*)d_in[5];
    const int* pW = (const int*)d_in[6];

    int Nv = in_sizes[1] / (BB * 2);
    int N = in_sizes[3] / 3;
    int K = in_sizes[4] / 3;

    // workspace layout (floats): fmT | depth | params
    float* fmT = (float*)d_ws;
    float* depth = fmT + (size_t)BB * CC * HF * WF;          // 8,388,608 floats
    float* params = depth + (size_t)BB * 512 * 512;          // +1,048,576 floats (16B aligned)

    float* out_lf = (float*)d_out;
    float* out_vw = out_lf + (size_t)BB * N * CC;
    float* out_c3 = out_vw + (size_t)BB * N;

    hipLaunchKernelGGL(transpose_fm, dim3(HF * WF / 32, CC / 32, BB), dim3(32, 8), 0, stream,
                       fm, fmT);
    hipLaunchKernelGGL(depth_init, dim3(2048), dim3(256), 0, stream, depth, pH, pW);
    hipLaunchKernelGGL(depth_scatter, dim3((BB * Nv + 255) / 256), dim3(256), 0, stream,
                       v2d, v3d, depth, Nv, pH, pW);
    hipLaunchKernelGGL(point_setup, dim3((BB * N + 255) / 256), dim3(256), 0, stream,
                       v2d, v3d, parents, bary, depth, out_vw, out_c3, (float4*)params,
                       N, Nv, K, pH, pW);
    hipLaunchKernelGGL(gather_feats, dim3((BB * N * 32 + 255) / 256), dim3(256), 0, stream,
                       fmT, (const float4*)params, out_lf, N);
}